// Round 1
// baseline (6156.876 us; speedup 1.0000x reference)
//
#include <hip/hip_runtime.h>

#define BB 1024
#define FF 64
#define SS 512
#define HH 128

// ---------------------------------------------------------------------------
// Recurrence kernel: one block per batch row. 512 threads; thread j owns gate
// column j (i:0..127, f:128..255, g:256..383, o:384..511). Weights held in
// registers for the whole sequence; h broadcast from LDS. Early exit at
// t == predict_len[b]; the tail (t >= P) is written by tail_copy.
// ---------------------------------------------------------------------------
__global__ __launch_bounds__(512, 2)
void lstm_seq_kernel(const float* __restrict__ x,
                     const int* __restrict__ available_len,
                     const int* __restrict__ predict_len,
                     const float* __restrict__ W_ih,
                     const float* __restrict__ W_hh,
                     const float* __restrict__ b_ih,
                     const float* __restrict__ b_hh,
                     const float* __restrict__ W_den,
                     const float* __restrict__ b_den,
                     const float* __restrict__ init_ch,
                     float* __restrict__ out)
{
    const int b = blockIdx.x;
    const int j = threadIdx.x;            // 0..511 gate column
    const int avail = available_len[b];
    const int P     = predict_len[b];     // >= 1 always

    __shared__ __align__(16) float sh_inp[FF];     // current input (64)
    __shared__ __align__(16) float sh_h[HH];       // hidden state (128)
    __shared__ __align__(16) float sh_gates[4*HH]; // 512 gates

    // --- register-stationary weights -------------------------------------
    float wih[FF];    // W_ih[j][0:64]
    float whh[HH];    // W_hh[j][0:128]
    float wden[16];   // W_den[j>>3][(j&7)*16 : +16]
    {
        const float4* p4 = reinterpret_cast<const float4*>(W_ih + j*FF);
        #pragma unroll
        for (int k=0;k<FF/4;k++){ float4 v=p4[k]; wih[4*k]=v.x; wih[4*k+1]=v.y; wih[4*k+2]=v.z; wih[4*k+3]=v.w; }
    }
    {
        const float4* p4 = reinterpret_cast<const float4*>(W_hh + j*HH);
        #pragma unroll
        for (int k=0;k<HH/4;k++){ float4 v=p4[k]; whh[4*k]=v.x; whh[4*k+1]=v.y; whh[4*k+2]=v.z; whh[4*k+3]=v.w; }
    }
    const int f_pred = j >> 3;
    const int kc     = j & 7;
    {
        const float4* p4 = reinterpret_cast<const float4*>(W_den + f_pred*HH + kc*16);
        #pragma unroll
        for (int k=0;k<4;k++){ float4 v=p4[k]; wden[4*k]=v.x; wden[4*k+1]=v.y; wden[4*k+2]=v.z; wden[4*k+3]=v.w; }
    }
    const float bsum = b_ih[j] + b_hh[j];
    const float bden = b_den[f_pred];

    float c = 0.f;
    if (j < HH) { c = init_ch[j]; sh_h[j] = init_ch[HH + j]; }

    const float* xrow = x + (size_t)b*FF*SS;
    float*       outb = out + (size_t)b*FF;

    for (int t = 0; t < P; ++t) {
        // observed phase: input = x[:, :, t]; else sh_inp already holds pred_{t-1}
        if (t < avail && j < FF) sh_inp[j] = xrow[j*SS + t];
        __syncthreads();   // B1: sh_inp (and, at t=0, sh_h init) visible

        // gates[j] = b + inp . W_ih[j] + h . W_hh[j]
        float g0=0.f, g1=0.f, g2=0.f, g3=0.f;
        const float4* in4 = reinterpret_cast<const float4*>(sh_inp);
        #pragma unroll
        for (int k=0;k<FF/4;k++){
            float4 v = in4[k];
            g0 = fmaf(v.x, wih[4*k+0], g0);
            g1 = fmaf(v.y, wih[4*k+1], g1);
            g2 = fmaf(v.z, wih[4*k+2], g2);
            g3 = fmaf(v.w, wih[4*k+3], g3);
        }
        const float4* h4 = reinterpret_cast<const float4*>(sh_h);
        #pragma unroll
        for (int k=0;k<HH/4;k++){
            float4 v = h4[k];
            g0 = fmaf(v.x, whh[4*k+0], g0);
            g1 = fmaf(v.y, whh[4*k+1], g1);
            g2 = fmaf(v.z, whh[4*k+2], g2);
            g3 = fmaf(v.w, whh[4*k+3], g3);
        }
        sh_gates[j] = bsum + ((g0+g1)+(g2+g3));
        __syncthreads();   // B2: gates ready; all sh_h reads done

        // cell update (threads 0..127 own hidden unit j)
        if (j < HH) {
            float gi = sh_gates[j];
            float gf = sh_gates[j +   HH];
            float gg = sh_gates[j + 2*HH];
            float go = sh_gates[j + 3*HH];
            float si = 1.f/(1.f + __expf(-gi));
            float sf = 1.f/(1.f + __expf(-gf));
            float so = 1.f/(1.f + __expf(-go));
            float tg = 1.f - 2.f/(__expf(2.f*gg) + 1.f);   // tanh, overflow-safe
            c = sf*c + si*tg;
            float tc = 1.f - 2.f/(__expf(2.f*c) + 1.f);
            sh_h[j] = so*tc;   // h_new
        }
        __syncthreads();   // B3: h_new ready

        // pred[f] = h_new . W_den[f] + b_den[f]; 8 lanes per f, shfl-reduce
        {
            const float4* hh4 = reinterpret_cast<const float4*>(sh_h + kc*16);
            float p0=0.f, p1=0.f;
            #pragma unroll
            for (int k=0;k<4;k++){
                float4 v = hh4[k];
                p0 = fmaf(v.x, wden[4*k+0], p0);
                p1 = fmaf(v.y, wden[4*k+1], p1);
                p0 = fmaf(v.z, wden[4*k+2], p0);
                p1 = fmaf(v.w, wden[4*k+3], p1);
            }
            float p = p0 + p1;
            p += __shfl_xor(p, 1);
            p += __shfl_xor(p, 2);
            p += __shfl_xor(p, 4);
            if (kc == 0) {
                p += bden;
                outb[(size_t)t*BB*FF + f_pred] = p;          // out[t][b][f]
                if (t+1 >= avail) sh_inp[f_pred] = p;        // autoregressive feedback
            }
        }
        // next-iter B1 orders the sh_inp writes vs. the next gate reads
    }
}

// ---------------------------------------------------------------------------
// Tail: for t >= predict_len[b], out[t][b][f] = x[b][f][t] (a 64xS transpose
// per row). One block per (b, 64-wide t-chunk), LDS transpose, both sides
// coalesced.
// ---------------------------------------------------------------------------
__global__ void tail_copy(const float* __restrict__ x,
                          const int* __restrict__ predict_len,
                          float* __restrict__ out)
{
    __shared__ float tile[64][65];
    const int b  = blockIdx.x;
    const int t0 = blockIdx.y * 64;
    const int P  = predict_len[b];
    if (t0 + 64 <= P) return;            // chunk fully covered by recurrence

    const int tid = threadIdx.x;         // 256
    const int tt  = tid & 63;
    const int fb  = tid >> 6;            // 0..3
    #pragma unroll
    for (int i=0;i<16;i++){
        int f = fb*16 + i;
        tile[f][tt] = x[(size_t)b*FF*SS + (size_t)f*SS + t0 + tt];
    }
    __syncthreads();
    const int f2 = tid & 63;
    const int tb = tid >> 6;
    #pragma unroll
    for (int i=0;i<16;i++){
        int tloc = tb*16 + i;
        int t    = t0 + tloc;
        if (t >= P) out[(size_t)t*BB*FF + (size_t)b*FF + f2] = tile[f2][tloc];
    }
}

extern "C" void kernel_launch(void* const* d_in, const int* in_sizes, int n_in,
                              void* d_out, int out_size, void* d_ws, size_t ws_size,
                              hipStream_t stream) {
    const float* x        = (const float*)d_in[0];
    const int*   avail    = (const int*)  d_in[1];
    const int*   plen     = (const int*)  d_in[2];
    const float* W_ih     = (const float*)d_in[3];
    const float* W_hh     = (const float*)d_in[4];
    const float* b_ih     = (const float*)d_in[5];
    const float* b_hh     = (const float*)d_in[6];
    const float* W_den    = (const float*)d_in[7];
    const float* b_den    = (const float*)d_in[8];
    const float* init_ch  = (const float*)d_in[9];
    float*       out      = (float*)d_out;

    tail_copy<<<dim3(BB, SS/64), dim3(256), 0, stream>>>(x, plen, out);
    lstm_seq_kernel<<<dim3(BB), dim3(512), 0, stream>>>(
        x, avail, plen, W_ih, W_hh, b_ih, b_hh, W_den, b_den, init_ch, out);
}

// Round 2
// 484.749 us; speedup vs baseline: 12.7012x; 12.7012x over previous
//
#include <hip/hip_runtime.h>

#define BB 1024
#define FF 64
#define SS 512
#define HH 128
#define ZP 200          // z row pitch in bf16 elems (192 data + 8 pad -> conflict-free ds_read_b128)
#define ZROWS 16

typedef __attribute__((ext_vector_type(8))) short bf16x8;   // 8 bf16 = 4 VGPR (guide-verified frag type)
typedef __attribute__((ext_vector_type(4))) float f32x4;

__device__ __forceinline__ unsigned short f2bf(float f) {
    unsigned int u = __float_as_uint(f);
    u += 0x7fff + ((u >> 16) & 1);          // RNE
    return (unsigned short)(u >> 16);
}

__device__ __forceinline__ bf16x8 pack8(const float* v) {
    bf16x8 r;
    #pragma unroll
    for (int i = 0; i < 8; i++) r[i] = (short)f2bf(v[i]);
    return r;
}

// ---------------------------------------------------------------------------
// 256 blocks x 512 threads (8 waves). Block owns 4 batch rows, placed at
// M-rows {0,4,8,12} of the 16-row MFMA tile so real rows sit in acc reg 0.
// Wave w owns hidden units [16w,16w+16): gate cols {16w+128g}. Weights are
// bf16 B-fragments in registers (96 VGPR). z=[inp|h] bf16 in LDS, dbuf'd.
// ---------------------------------------------------------------------------
__global__ __launch_bounds__(512, 2)
void lstm_mfma_kernel(const float* __restrict__ x,
                      const int* __restrict__ available_len,
                      const int* __restrict__ predict_len,
                      const float* __restrict__ W_ih,
                      const float* __restrict__ W_hh,
                      const float* __restrict__ b_ih,
                      const float* __restrict__ b_hh,
                      const float* __restrict__ W_den,
                      const float* __restrict__ b_den,
                      const float* __restrict__ init_ch,
                      float* __restrict__ out)
{
    const int b0  = blockIdx.x * 4;
    const int tid = threadIdx.x;
    const int w   = tid >> 6;          // wave 0..7
    const int l   = tid & 63;
    const int l16 = l & 15;
    const int lq  = l >> 4;            // 0..3

    __shared__ __align__(16) unsigned short zbuf[2][ZROWS * ZP];

    // zero both z buffers (garbage M-rows must read as 0)
    for (int i = tid; i < 2 * ZROWS * ZP / 2; i += 512)
        ((unsigned int*)zbuf)[i] = 0u;

    // per-row meta (named scalars, no runtime-indexed arrays)
    const int p0 = predict_len[b0], p1 = predict_len[b0+1],
              p2 = predict_len[b0+2], p3 = predict_len[b0+3];
    const int maxP = max(max(p0, p1), max(p2, p3));
    const int P_my  = predict_len[b0 + lq];     // row this lane owns (acc reg 0)
    const int AV_my = available_len[b0 + lq];

    // ---- weight fragments (one-time, bf16, register-resident) ----
    bf16x8 wg[4][6];                    // [gate][ktile], 96 VGPR
    float bias[4];
    #pragma unroll
    for (int g = 0; g < 4; ++g) {
        const int n = 128*g + 16*w + l16;
        const float* rih = W_ih + n * FF;
        const float* rhh = W_hh + n * HH;
        #pragma unroll
        for (int kt = 0; kt < 6; ++kt) {
            const int k = 32*kt + 8*lq;                 // [0,192)
            const float* src = (k < 64) ? (rih + k) : (rhh + (k - 64));
            float tmp[8];
            #pragma unroll
            for (int i = 0; i < 8; i++) tmp[i] = src[i];
            wg[g][kt] = pack8(tmp);
        }
        bias[g] = b_ih[n] + b_hh[n];
    }

    // pred weights on waves 0..3 (f = 16w + l16)
    bf16x8 wd0, wd1, wd2, wd3;
    float bden = 0.f;
    size_t xbase = 0;
    int AV_x = 0;
    if (w < 4) {
        const int f = 16*w + l16;
        const float* rd = W_den + f * HH;
        float tmp[8];
        #pragma unroll
        for (int i = 0; i < 8; i++) tmp[i] = rd[0*32 + 8*lq + i];
        wd0 = pack8(tmp);
        #pragma unroll
        for (int i = 0; i < 8; i++) tmp[i] = rd[1*32 + 8*lq + i];
        wd1 = pack8(tmp);
        #pragma unroll
        for (int i = 0; i < 8; i++) tmp[i] = rd[2*32 + 8*lq + i];
        wd2 = pack8(tmp);
        #pragma unroll
        for (int i = 0; i < 8; i++) tmp[i] = rd[3*32 + 8*lq + i];
        wd3 = pack8(tmp);
        bden = b_den[f];
        // x duty: wave w<4 handles batch row (b0+w), feature l
        xbase = ((size_t)(b0 + w) * FF + l) * SS;
        AV_x  = available_len[b0 + w];
    }

    // state
    const int unit = 16*w + l16;
    float c = init_ch[unit];
    const float h0 = init_ch[HH + unit];

    __syncthreads();                    // zeroing done before init writes

    // init buf0: h + x_0 (t=0 < avail always, avail >= 1)
    zbuf[0][(4*lq)*ZP + 64 + unit] = f2bf(h0);
    if (w < 4) {
        float xv0 = x[xbase + 0];
        zbuf[0][(4*w)*ZP + l] = f2bf(xv0);
    }

    int cur = 0;
    for (int t = 0; t < maxP; ++t) {
        __syncthreads();                               // B1: buf[cur] complete

        // A fragments (rows l16, K-tile kt) from buf[cur]
        const unsigned short* zc = zbuf[cur];
        bf16x8 a0 = *(const bf16x8*)(zc + l16*ZP +   0 + 8*lq);
        bf16x8 a1 = *(const bf16x8*)(zc + l16*ZP +  32 + 8*lq);
        bf16x8 a2 = *(const bf16x8*)(zc + l16*ZP +  64 + 8*lq);
        bf16x8 a3 = *(const bf16x8*)(zc + l16*ZP +  96 + 8*lq);
        bf16x8 a4 = *(const bf16x8*)(zc + l16*ZP + 128 + 8*lq);
        bf16x8 a5 = *(const bf16x8*)(zc + l16*ZP + 160 + 8*lq);

        // prefetch x_{t+1} (hidden under MFMA+cell)
        float xv = 0.f;
        const bool xload = (w < 4) && (t + 1 < AV_x);
        if (xload) xv = x[xbase + t + 1];

        // gates: wave's 4 gate col-tiles share the A frags
        float gate0, gate1, gate2, gate3;
        {
            f32x4 acc = {0.f, 0.f, 0.f, 0.f};
            acc = __builtin_amdgcn_mfma_f32_16x16x32_bf16(a0, wg[0][0], acc, 0,0,0);
            acc = __builtin_amdgcn_mfma_f32_16x16x32_bf16(a1, wg[0][1], acc, 0,0,0);
            acc = __builtin_amdgcn_mfma_f32_16x16x32_bf16(a2, wg[0][2], acc, 0,0,0);
            acc = __builtin_amdgcn_mfma_f32_16x16x32_bf16(a3, wg[0][3], acc, 0,0,0);
            acc = __builtin_amdgcn_mfma_f32_16x16x32_bf16(a4, wg[0][4], acc, 0,0,0);
            acc = __builtin_amdgcn_mfma_f32_16x16x32_bf16(a5, wg[0][5], acc, 0,0,0);
            gate0 = acc[0] + bias[0];
        }
        {
            f32x4 acc = {0.f, 0.f, 0.f, 0.f};
            acc = __builtin_amdgcn_mfma_f32_16x16x32_bf16(a0, wg[1][0], acc, 0,0,0);
            acc = __builtin_amdgcn_mfma_f32_16x16x32_bf16(a1, wg[1][1], acc, 0,0,0);
            acc = __builtin_amdgcn_mfma_f32_16x16x32_bf16(a2, wg[1][2], acc, 0,0,0);
            acc = __builtin_amdgcn_mfma_f32_16x16x32_bf16(a3, wg[1][3], acc, 0,0,0);
            acc = __builtin_amdgcn_mfma_f32_16x16x32_bf16(a4, wg[1][4], acc, 0,0,0);
            acc = __builtin_amdgcn_mfma_f32_16x16x32_bf16(a5, wg[1][5], acc, 0,0,0);
            gate1 = acc[0] + bias[1];
        }
        {
            f32x4 acc = {0.f, 0.f, 0.f, 0.f};
            acc = __builtin_amdgcn_mfma_f32_16x16x32_bf16(a0, wg[2][0], acc, 0,0,0);
            acc = __builtin_amdgcn_mfma_f32_16x16x32_bf16(a1, wg[2][1], acc, 0,0,0);
            acc = __builtin_amdgcn_mfma_f32_16x16x32_bf16(a2, wg[2][2], acc, 0,0,0);
            acc = __builtin_amdgcn_mfma_f32_16x16x32_bf16(a3, wg[2][3], acc, 0,0,0);
            acc = __builtin_amdgcn_mfma_f32_16x16x32_bf16(a4, wg[2][4], acc, 0,0,0);
            acc = __builtin_amdgcn_mfma_f32_16x16x32_bf16(a5, wg[2][5], acc, 0,0,0);
            gate2 = acc[0] + bias[2];
        }
        {
            f32x4 acc = {0.f, 0.f, 0.f, 0.f};
            acc = __builtin_amdgcn_mfma_f32_16x16x32_bf16(a0, wg[3][0], acc, 0,0,0);
            acc = __builtin_amdgcn_mfma_f32_16x16x32_bf16(a1, wg[3][1], acc, 0,0,0);
            acc = __builtin_amdgcn_mfma_f32_16x16x32_bf16(a2, wg[3][2], acc, 0,0,0);
            acc = __builtin_amdgcn_mfma_f32_16x16x32_bf16(a3, wg[3][3], acc, 0,0,0);
            acc = __builtin_amdgcn_mfma_f32_16x16x32_bf16(a4, wg[3][4], acc, 0,0,0);
            acc = __builtin_amdgcn_mfma_f32_16x16x32_bf16(a5, wg[3][5], acc, 0,0,0);
            gate3 = acc[0] + bias[3];
        }

        // cell update (1 real row per lane: acc reg 0)
        const float si = 1.f / (1.f + __expf(-gate0));
        const float sf = 1.f / (1.f + __expf(-gate1));
        const float tg = 1.f - 2.f / (__expf(2.f * gate2) + 1.f);
        const float so = 1.f / (1.f + __expf(-gate3));
        const float cn = sf * c + si * tg;
        const float tc = 1.f - 2.f / (__expf(2.f * cn) + 1.f);
        const float hn = so * tc;

        const bool sel = (t < P_my);
        if (sel) c = cn;

        const int nxt = cur ^ 1;
        if (sel) zbuf[nxt][(4*lq)*ZP + 64 + unit] = f2bf(hn);   // h for t+1
        if (xload) zbuf[nxt][(4*w)*ZP + l] = f2bf(xv);          // x for t+1

        __syncthreads();                               // B2: buf[nxt] h ready

        if (w < 4) {
            const unsigned short* zn = zbuf[nxt];
            bf16x8 h0f = *(const bf16x8*)(zn + l16*ZP + 64 +  0 + 8*lq);
            bf16x8 h1f = *(const bf16x8*)(zn + l16*ZP + 64 + 32 + 8*lq);
            bf16x8 h2f = *(const bf16x8*)(zn + l16*ZP + 64 + 64 + 8*lq);
            bf16x8 h3f = *(const bf16x8*)(zn + l16*ZP + 64 + 96 + 8*lq);
            f32x4 pacc = {0.f, 0.f, 0.f, 0.f};
            pacc = __builtin_amdgcn_mfma_f32_16x16x32_bf16(h0f, wd0, pacc, 0,0,0);
            pacc = __builtin_amdgcn_mfma_f32_16x16x32_bf16(h1f, wd1, pacc, 0,0,0);
            pacc = __builtin_amdgcn_mfma_f32_16x16x32_bf16(h2f, wd2, pacc, 0,0,0);
            pacc = __builtin_amdgcn_mfma_f32_16x16x32_bf16(h3f, wd3, pacc, 0,0,0);
            const float pred = pacc[0] + bden;
            // lane writes (row b0+lq, f = 16w + l16)
            if (t < P_my) {
                out[(size_t)t * BB * FF + (size_t)(b0 + lq) * FF + 16*w + l16] = pred;
                if (t + 1 >= AV_my && t + 1 < P_my)            // feedback input
                    zbuf[nxt][(4*lq)*ZP + 16*w + l16] = f2bf(pred);
            }
        }
        cur = nxt;
    }
}

// ---------------------------------------------------------------------------
// Tail: for t >= predict_len[b], out[t][b][f] = x[b][f][t].
// ---------------------------------------------------------------------------
__global__ void tail_copy(const float* __restrict__ x,
                          const int* __restrict__ predict_len,
                          float* __restrict__ out)
{
    __shared__ float tile[64][65];
    const int b  = blockIdx.x;
    const int t0 = blockIdx.y * 64;
    const int P  = predict_len[b];
    if (t0 + 64 <= P) return;

    const int tid = threadIdx.x;         // 256
    const int tt  = tid & 63;
    const int fb  = tid >> 6;
    #pragma unroll
    for (int i = 0; i < 16; i++) {
        int f = fb * 16 + i;
        tile[f][tt] = x[(size_t)b * FF * SS + (size_t)f * SS + t0 + tt];
    }
    __syncthreads();
    const int f2 = tid & 63;
    const int tb = tid >> 6;
    #pragma unroll
    for (int i = 0; i < 16; i++) {
        int tloc = tb * 16 + i;
        int t    = t0 + tloc;
        if (t >= P) out[(size_t)t * BB * FF + (size_t)b * FF + f2] = tile[f2][tloc];
    }
}

extern "C" void kernel_launch(void* const* d_in, const int* in_sizes, int n_in,
                              void* d_out, int out_size, void* d_ws, size_t ws_size,
                              hipStream_t stream) {
    const float* x       = (const float*)d_in[0];
    const int*   avail   = (const int*)  d_in[1];
    const int*   plen    = (const int*)  d_in[2];
    const float* W_ih    = (const float*)d_in[3];
    const float* W_hh    = (const float*)d_in[4];
    const float* b_ih    = (const float*)d_in[5];
    const float* b_hh    = (const float*)d_in[6];
    const float* W_den   = (const float*)d_in[7];
    const float* b_den   = (const float*)d_in[8];
    const float* init_ch = (const float*)d_in[9];
    float*       out     = (float*)d_out;

    tail_copy<<<dim3(BB, SS/64), dim3(256), 0, stream>>>(x, plen, out);
    lstm_mfma_kernel<<<dim3(BB/4), dim3(512), 0, stream>>>(
        x, avail, plen, W_ih, W_hh, b_ih, b_hh, W_den, b_den, init_ch, out);
}